// Round 4
// baseline (1388.789 us; speedup 1.0000x reference)
//
#include <hip/hip_runtime.h>

#define N_ 8
#define C_ 64
#define H_ 128
#define W_ 512
#define CO_ 64
#define HW_ (H_*W_)
#define NTAP 9

typedef short s8v __attribute__((ext_vector_type(8)));   // 8 bf16 in 4 VGPRs
typedef float f16v __attribute__((ext_vector_type(16))); // 32x32 acc
typedef float f2v __attribute__((ext_vector_type(2)));   // (dy,dx) pair

__device__ __forceinline__ unsigned short f2bf(float f) {
    unsigned u = __float_as_uint(f);
    u += 0x7FFF + ((u >> 16) & 1u);     // round-to-nearest-even
    return (unsigned short)(u >> 16);
}
__device__ __forceinline__ unsigned packbf(float a, float b) {
    return (unsigned)f2bf(a) | ((unsigned)f2bf(b) << 16);
}

// ---------------------------------------------------------------------------
// Prep: w_def [co][c][3][3] -> wTb bf16 [t][co][c]  (B-operand: k=c contiguous)
//       w_off [18][c][3][3] -> wOb bf16 [t][32][c]  (och padded 18->32 w/ 0)
// ---------------------------------------------------------------------------
__global__ void k_prep_w(const float* __restrict__ w_def,
                         const float* __restrict__ w_off,
                         unsigned short* __restrict__ wTb,
                         unsigned short* __restrict__ wOb) {
    int idx = blockIdx.x * 256 + threadIdx.x;
    if (idx < NTAP * CO_ * C_) {
        int t = idx / (CO_ * C_);
        int r = idx % (CO_ * C_);
        int co = r / C_, c = r % C_;
        wTb[idx] = f2bf(w_def[(co * C_ + c) * NTAP + t]);
    }
    if (idx < NTAP * 32 * C_) {
        int t = idx / (32 * C_);
        int r = idx % (32 * C_);
        int oc = r / C_, c = r % C_;
        float v = (oc < 18) ? w_off[(oc * C_ + c) * NTAP + t] : 0.f;
        wOb[idx] = f2bf(v);
    }
}

// ---------------------------------------------------------------------------
// NCHW f32 -> NHWC f32 transpose: x_t[n][y][x][c], px record = 256 B.
// Tile: 64 ch x 64 px through LDS, both sides coalesced.
// ---------------------------------------------------------------------------
__global__ __launch_bounds__(256) void k_tr(const float* __restrict__ x,
                                            float* __restrict__ x_t) {
    __shared__ float T[64][65];
    int b = blockIdx.x;
    int n = b >> 10;              // 1024 blocks/image = 128 y * 8 xchunks
    int rem = b & 1023;
    int y = rem >> 3;
    int x0 = (rem & 7) << 6;
    int tid = threadIdx.x;
    int q = tid >> 6, r = tid & 63;

    const float* xp = x + ((size_t)(n * C_) * H_ + y) * W_ + x0;
    #pragma unroll
    for (int k = 0; k < 16; k++) {
        int c = k * 4 + q;
        T[c][r] = xp[(size_t)c * HW_ + r];
    }
    __syncthreads();
    float* op = x_t + ((size_t)(n * H_ + y) * W_ + x0) * 64;
    #pragma unroll
    for (int k = 0; k < 16; k++) {
        int px = k * 4 + q;
        op[(size_t)px * 64 + r] = T[r][px];
    }
}

// ---------------------------------------------------------------------------
// Offset conv as MFMA GEMM: M=128px/block, K=576 (9 taps x 64c), N=32 (18 used)
// Staging from NHWC x_t: thread p loads its 32-ch half of px (xb+p+j-1, yy)
// as 8 dense dwordx4 (vs 32 scalar strided dwords from NCHW).
// B-fragments direct from global wOb (36 KB, cache resident).
// ---------------------------------------------------------------------------
__global__ __launch_bounds__(256, 6) void k_off_mfma(
        const float* __restrict__ x_t,
        const unsigned short* __restrict__ wOb,
        const float* __restrict__ b_off,
        float* __restrict__ off_ws) {
    __shared__ __align__(16) char smem[17408];
    char* S  = smem;              // [128][68] bf16 = 17408 B
    float* E = (float*)smem;      // [128][33] f32 = 16896 B (epilogue reuse)

    int tid = threadIdx.x;
    int b = blockIdx.x;
    int n = b & 7;
    int lidx = b >> 3;
    int y = lidx >> 2;
    int xb = (lidx & 3) << 7;
    int lane = tid & 63, wave = tid >> 6;
    int p = tid & 127, cg = tid >> 7;
    int la = lane & 31, kh = lane >> 5;

    f16v acc;
    #pragma unroll
    for (int r = 0; r < 16; r++) acc[r] = 0.f;

    char* sp = S + p * 136 + cg * 64;

    for (int t = 0; t < NTAP; t++) {
        int yy = y + (t / 3) - 1;
        if (yy < 0 || yy >= H_) continue;   // block-uniform; skip = zero row
        int xx = xb + p + (t % 3) - 1;
        bool ok = (xx >= 0) && (xx < W_);
        int xs = min(max(xx, 0), W_ - 1);
        const char* src = (const char*)x_t
            + (((size_t)((n * H_ + yy) * W_) + xs) << 8) + cg * 128;
        __syncthreads();
        #pragma unroll
        for (int g = 0; g < 8; g++) {
            float4 c4 = *(const float4*)(src + g * 16);
            float v0 = ok ? c4.x : 0.f;
            float v1 = ok ? c4.y : 0.f;
            float v2 = ok ? c4.z : 0.f;
            float v3 = ok ? c4.w : 0.f;
            *(unsigned long long*)(sp + g * 8) =
                (unsigned long long)packbf(v0, v1)
              | ((unsigned long long)packbf(v2, v3) << 32);
        }
        __syncthreads();
        // MFMA: wave w -> px block w*32; och 0..31; B direct from global
        {
            const char* ap = S + (wave * 32 + la) * 136 + kh * 16;
            const char* gb = (const char*)wOb + t * 4096 + la * 128 + kh * 16;
            #pragma unroll
            for (int ks = 0; ks < 4; ks++) {
                s8v a, bf;
                *(long*)&a = *(const long*)ap;
                *((long*)&a + 1) = *(const long*)(ap + 8);
                bf = *(const s8v*)(gb + ks * 32);
                ap += 32;
                acc = __builtin_amdgcn_mfma_f32_32x32x16_bf16(a, bf, acc, 0, 0, 0);
            }
        }
    }
    __syncthreads();
    // epilogue: C/D layout col=lane&31 (och), row=(r&3)+8*(r>>2)+4*(lane>>5) (px)
    {
        int lh = lane >> 5;
        #pragma unroll
        for (int r = 0; r < 16; r++) {
            int pxl = wave * 32 + (r & 3) + 8 * (r >> 2) + 4 * lh;
            E[pxl * 33 + la] = acc[r];
        }
    }
    __syncthreads();
    {
        size_t base = ((size_t)(n * H_ + y) * W_ + xb) * 18;
        #pragma unroll
        for (int k = 0; k < 9; k++) {
            int f = tid + k * 256;
            int pp = f / 18, oc = f % 18;
            off_ws[base + f] = E[pp * 33 + oc] + b_off[oc];
        }
    }
}

// ---------------------------------------------------------------------------
// Bilinear metadata: 4 weights (validity folded) + 4 clamped linear offsets
// ---------------------------------------------------------------------------
__device__ __forceinline__ void bilin_meta(float py, float px,
        float& w00, float& w01, float& w10, float& w11,
        int& o00, int& o01, int& o10, int& o11) {
    float fy0 = floorf(py), fx0 = floorf(px);
    int iy0 = (int)fy0, ix0 = (int)fx0;
    int iy1 = iy0 + 1,  ix1 = ix0 + 1;
    float ly = py - fy0, lx = px - fx0;
    float hy = 1.f - ly, hx = 1.f - lx;
    bool y0ok = (iy0 >= 0) && (iy0 < H_);
    bool y1ok = (iy1 >= 0) && (iy1 < H_);
    bool x0ok = (ix0 >= 0) && (ix0 < W_);
    bool x1ok = (ix1 >= 0) && (ix1 < W_);
    w00 = hy * hx * ((y0ok && x0ok) ? 1.f : 0.f);
    w01 = hy * lx * ((y0ok && x1ok) ? 1.f : 0.f);
    w10 = ly * hx * ((y1ok && x0ok) ? 1.f : 0.f);
    w11 = ly * lx * ((y1ok && x1ok) ? 1.f : 0.f);
    int y0c = min(max(iy0, 0), H_ - 1), y1c = min(max(iy1, 0), H_ - 1);
    int x0c = min(max(ix0, 0), W_ - 1), x1c = min(max(ix1, 0), W_ - 1);
    o00 = y0c * W_ + x0c; o01 = y0c * W_ + x1c;
    o10 = y1c * W_ + x0c; o11 = y1c * W_ + x1c;
}

// ---------------------------------------------------------------------------
// Deformable conv as fused sample+MFMA GEMM: M=128px/block, K=576, N=64.
// r0 register-lean skeleton (one-pass epilogue, no spill: WRITE must be
// exactly 128 MiB) + NHWC gather: per corner one float4 per 4-ch group,
// 8 groups, all addresses known at loop entry -> compiler pipelines depth
// to the 128-reg cap. LDS 34304 -> 4 blocks/CU (L2 working-front sweet spot).
// ---------------------------------------------------------------------------
__global__ __launch_bounds__(256, 4) void k_deform(
        const float* __restrict__ x_t,
        const float* __restrict__ off_ws,
        const unsigned short* __restrict__ wTb,
        const float* __restrict__ b_def,
        float* __restrict__ out) {
    __shared__ __align__(16) char smem[34304];
    char* S  = smem;              // [128][68] bf16 = 17408 B
    float* E = (float*)smem;      // [128][67] f32 = 34304 B (one-pass epilogue)

    int tid = threadIdx.x;
    int b = blockIdx.x;
    int n = b & 7;                 // image <-> XCD for L2 locality
    int lidx = b >> 3;
    int y = lidx >> 2;
    int xb = (lidx & 3) << 7;
    int lane = tid & 63, wave = tid >> 6;
    int p = tid & 127, cg = tid >> 7;
    int la = lane & 31, kh = lane >> 5;

    f16v acc0, acc1;
    #pragma unroll
    for (int r = 0; r < 16; r++) { acc0[r] = 0.f; acc1[r] = 0.f; }

    const char* xtn = (const char*)x_t + ((size_t)n * HW_ << 8) + cg * 128;
    size_t pix = (size_t)(n * H_ + y) * W_ + xb + p;
    const f2v* offp = (const f2v*)off_ws + pix * 9;
    char* sp = S + p * 136 + cg * 64;

    for (int t = 0; t < NTAP; t++) {
        // meta + corner addresses BEFORE the barrier (offp latency hides)
        f2v od = offp[t];
        float py = (float)(y + (t / 3) - 1) + od[0];
        float pxf = (float)(xb + p + (t % 3) - 1) + od[1];
        float w00, w01, w10, w11;
        int o00, o01, o10, o11;
        bilin_meta(py, pxf, w00, w01, w10, w11, o00, o01, o10, o11);
        const char* a00 = xtn + ((size_t)o00 << 8);
        const char* a01 = xtn + ((size_t)o01 << 8);
        const char* a10 = xtn + ((size_t)o10 << 8);
        const char* a11 = xtn + ((size_t)o11 << 8);

        __syncthreads();           // S readers from prev tap done
        // 8 groups x 4 channels: 4 float4 (16 regs) live per group
        #pragma unroll
        for (int g = 0; g < 8; g++) {
            float4 c00 = *(const float4*)(a00 + g * 16);
            float4 c01 = *(const float4*)(a01 + g * 16);
            float4 c10 = *(const float4*)(a10 + g * 16);
            float4 c11 = *(const float4*)(a11 + g * 16);
            float v0 = w00 * c00.x;
            v0 = fmaf(w01, c01.x, v0);
            v0 = fmaf(w10, c10.x, v0);
            v0 = fmaf(w11, c11.x, v0);
            float v1 = w00 * c00.y;
            v1 = fmaf(w01, c01.y, v1);
            v1 = fmaf(w10, c10.y, v1);
            v1 = fmaf(w11, c11.y, v1);
            float v2 = w00 * c00.z;
            v2 = fmaf(w01, c01.z, v2);
            v2 = fmaf(w10, c10.z, v2);
            v2 = fmaf(w11, c11.z, v2);
            float v3 = w00 * c00.w;
            v3 = fmaf(w01, c01.w, v3);
            v3 = fmaf(w10, c10.w, v3);
            v3 = fmaf(w11, c11.w, v3);
            *(unsigned long long*)(sp + g * 8) =
                (unsigned long long)packbf(v0, v1)
              | ((unsigned long long)packbf(v2, v3) << 32);
        }
        __syncthreads();
        // MFMA; B fragments straight from global (L1/L2-resident 72 KB table)
        {
            const char* ap = S + (wave * 32 + la) * 136 + kh * 16;
            const char* gb = (const char*)wTb + t * 8192 + la * 128 + kh * 16;
            #pragma unroll
            for (int ks = 0; ks < 4; ks++) {
                s8v a, b0, b1;
                *(long*)&a = *(const long*)ap;
                *((long*)&a + 1) = *(const long*)(ap + 8);
                b0 = *(const s8v*)(gb + ks * 32);
                b1 = *(const s8v*)(gb + 4096 + ks * 32);
                ap += 32;
                acc0 = __builtin_amdgcn_mfma_f32_32x32x16_bf16(a, b0, acc0, 0, 0, 0);
                acc1 = __builtin_amdgcn_mfma_f32_32x32x16_bf16(a, b1, acc1, 0, 0, 0);
            }
        }
    }
    __syncthreads();
    // one-pass epilogue (r0 structure): acc -> E [px][67] -> coalesced store
    {
        int lh = lane >> 5;
        #pragma unroll
        for (int r = 0; r < 16; r++) {
            int pxl = wave * 32 + (r & 3) + 8 * (r >> 2) + 4 * lh;
            E[pxl * 67 + la] = acc0[r];
            E[pxl * 67 + 32 + la] = acc1[r];
        }
    }
    __syncthreads();
    {
        int p0 = tid & 63;
        #pragma unroll
        for (int cb = 0; cb < 16; cb++) {
            int co = (cb << 2) + (tid >> 6);
            float bv = b_def[co];
            size_t ob = ((size_t)(n * CO_ + co) * H_ + y) * W_ + xb;
            out[ob + p0]      = E[p0 * 67 + co] + bv;
            out[ob + p0 + 64] = E[(p0 + 64) * 67 + co] + bv;
        }
    }
}

// ---------------------------------------------------------------------------
extern "C" void kernel_launch(void* const* d_in, const int* in_sizes, int n_in,
                              void* d_out, int out_size, void* d_ws, size_t ws_size,
                              hipStream_t stream) {
    const float* x     = (const float*)d_in[0];
    const float* w_off = (const float*)d_in[1];
    const float* b_off = (const float*)d_in[2];
    const float* w_def = (const float*)d_in[3];
    const float* b_def = (const float*)d_in[4];
    float* out = (float*)d_out;

    // ws: wTb @0 (72K), wOb @80K (36K), off_ws @256K (37.75 MB),
    //     x_t NHWC f32 @40M (134.2 MB) -> total ~175 MB
    unsigned short* wTb = (unsigned short*)d_ws;
    unsigned short* wOb = (unsigned short*)((char*)d_ws + 80 * 1024);
    float* off_ws       = (float*)((char*)d_ws + 256 * 1024);
    float* x_t          = (float*)((char*)d_ws + (size_t)40 * 1024 * 1024);

    hipLaunchKernelGGL(k_prep_w, dim3(144), dim3(256), 0, stream,
                       w_def, w_off, wTb, wOb);
    hipLaunchKernelGGL(k_tr, dim3(8192), dim3(256), 0, stream, x, x_t);
    hipLaunchKernelGGL(k_off_mfma, dim3(4096), dim3(256), 0, stream,
                       x_t, wOb, b_off, off_ws);
    hipLaunchKernelGGL(k_deform, dim3(4096), dim3(256), 0, stream,
                       x_t, off_ws, wTb, b_def, out);
}

// Round 5
// 796.791 us; speedup vs baseline: 1.7430x; 1.7430x over previous
//
#include <hip/hip_runtime.h>

#define N_ 8
#define C_ 64
#define H_ 128
#define W_ 512
#define CO_ 64
#define HW_ (H_*W_)
#define NTAP 9

typedef short s8v __attribute__((ext_vector_type(8)));   // 8 bf16 in 4 VGPRs
typedef float f16v __attribute__((ext_vector_type(16))); // 32x32 acc
typedef float f2v __attribute__((ext_vector_type(2)));   // (dy,dx) pair

__device__ __forceinline__ unsigned short f2bf(float f) {
    unsigned u = __float_as_uint(f);
    u += 0x7FFF + ((u >> 16) & 1u);     // round-to-nearest-even
    return (unsigned short)(u >> 16);
}
__device__ __forceinline__ unsigned packbf(float a, float b) {
    return (unsigned)f2bf(a) | ((unsigned)f2bf(b) << 16);
}
__device__ __forceinline__ float bf2f(unsigned short u) {
    return __uint_as_float(((unsigned)u) << 16);
}

// ---------------------------------------------------------------------------
// Prep: w_def [co][c][3][3] -> wTb bf16 [t][co][c]  (B-operand: k=c contiguous)
//       w_off [18][c][3][3] -> wOb bf16 [t][32][c]  (och padded 18->32 w/ 0)
// ---------------------------------------------------------------------------
__global__ void k_prep_w(const float* __restrict__ w_def,
                         const float* __restrict__ w_off,
                         unsigned short* __restrict__ wTb,
                         unsigned short* __restrict__ wOb) {
    int idx = blockIdx.x * 256 + threadIdx.x;
    if (idx < NTAP * CO_ * C_) {
        int t = idx / (CO_ * C_);
        int r = idx % (CO_ * C_);
        int co = r / C_, c = r % C_;
        wTb[idx] = f2bf(w_def[(co * C_ + c) * NTAP + t]);
    }
    if (idx < NTAP * 32 * C_) {
        int t = idx / (32 * C_);
        int r = idx % (32 * C_);
        int oc = r / C_, c = r % C_;
        float v = (oc < 18) ? w_off[(oc * C_ + c) * NTAP + t] : 0.f;
        wOb[idx] = f2bf(v);
    }
}

// ---------------------------------------------------------------------------
// NCHW f32 -> NHWC bf16: x_tb[n][y][x][c], px record = 128 B (2 cachelines).
// A lane's 32-ch corner half = 64 B = ONE full line, fully consumed.
// ---------------------------------------------------------------------------
__global__ __launch_bounds__(256) void k_tr(const float* __restrict__ x,
                                            unsigned short* __restrict__ x_tb) {
    __shared__ float T[64][65];
    int b = blockIdx.x;
    int n = b >> 10;              // 1024 blocks/image = 128 y * 8 xchunks
    int rem = b & 1023;
    int y = rem >> 3;
    int x0 = (rem & 7) << 6;
    int tid = threadIdx.x;
    int q = tid >> 6, r = tid & 63;

    const float* xp = x + ((size_t)(n * C_) * H_ + y) * W_ + x0;
    #pragma unroll
    for (int k = 0; k < 16; k++) {
        int c = k * 4 + q;
        T[c][r] = xp[(size_t)c * HW_ + r];
    }
    __syncthreads();
    // pack 2 ch -> u32; wave covers 2 px records (256 B contiguous)
    unsigned* op = (unsigned*)x_tb + ((size_t)(n * H_ + y) * W_ + x0) * 32;
    int c2 = tid & 31;
    #pragma unroll
    for (int k = 0; k < 8; k++) {
        int pxl = k * 8 + (tid >> 5);
        op[(size_t)pxl * 32 + c2] = packbf(T[2 * c2][pxl], T[2 * c2 + 1][pxl]);
    }
}

// ---------------------------------------------------------------------------
// Offset conv as MFMA GEMM: M=128px/block, K=576 (9 taps x 64c), N=32 (18 used)
// Staging from NHWC-bf16: 4 dwordx4 + OOB select + 4 LDS writes per tap
// (data already bf16 -- no pack). B direct from global wOb (36 KB, cached).
// LDS padded to pin 4 blocks/CU (L2 working-front sweet spot, r2 ablation).
// ---------------------------------------------------------------------------
__global__ __launch_bounds__(256, 4) void k_off_mfma(
        const unsigned short* __restrict__ x_tb,
        const unsigned short* __restrict__ wOb,
        const float* __restrict__ b_off,
        float* __restrict__ off_ws) {
    __shared__ __align__(16) char smem[36864];   // used 17408; pad pins 4 blk/CU
    char* S  = smem;              // [128][68] bf16 = 17408 B
    float* E = (float*)smem;      // [128][33] f32 = 16896 B (epilogue reuse)

    int tid = threadIdx.x;
    int b = blockIdx.x;
    int n = b & 7;
    int lidx = b >> 3;
    int y = lidx >> 2;
    int xb = (lidx & 3) << 7;
    int lane = tid & 63, wave = tid >> 6;
    int p = tid & 127, cg = tid >> 7;
    int la = lane & 31, kh = lane >> 5;

    f16v acc;
    #pragma unroll
    for (int r = 0; r < 16; r++) acc[r] = 0.f;

    char* sp = S + p * 136 + cg * 64;
    const char* xtn = (const char*)x_tb + ((size_t)n * HW_ << 7) + cg * 64;

    for (int t = 0; t < NTAP; t++) {
        int yy = y + (t / 3) - 1;
        if (yy < 0 || yy >= H_) continue;   // block-uniform; skip = zero row
        int xx = xb + p + (t % 3) - 1;
        bool ok = (xx >= 0) && (xx < W_);
        int xs = min(max(xx, 0), W_ - 1);
        const char* src = xtn + ((size_t)(yy * W_ + xs) << 7);
        __syncthreads();
        #pragma unroll
        for (int g = 0; g < 4; g++) {
            int4 c = *(const int4*)(src + g * 16);
            unsigned long long lo = ok ?
                ((unsigned long long)(unsigned)c.x |
                 ((unsigned long long)(unsigned)c.y << 32)) : 0ull;
            unsigned long long hi = ok ?
                ((unsigned long long)(unsigned)c.z |
                 ((unsigned long long)(unsigned)c.w << 32)) : 0ull;
            *(unsigned long long*)(sp + g * 16)     = lo;
            *(unsigned long long*)(sp + g * 16 + 8) = hi;
        }
        __syncthreads();
        // MFMA: wave w -> px block w*32; och 0..31; B direct from global
        {
            const char* ap = S + (wave * 32 + la) * 136 + kh * 16;
            const char* gb = (const char*)wOb + t * 4096 + la * 128 + kh * 16;
            #pragma unroll
            for (int ks = 0; ks < 4; ks++) {
                s8v a, bf;
                *(long*)&a = *(const long*)ap;
                *((long*)&a + 1) = *(const long*)(ap + 8);
                bf = *(const s8v*)(gb + ks * 32);
                ap += 32;
                acc = __builtin_amdgcn_mfma_f32_32x32x16_bf16(a, bf, acc, 0, 0, 0);
            }
        }
    }
    __syncthreads();
    // epilogue: C/D layout col=lane&31 (och), row=(r&3)+8*(r>>2)+4*(lane>>5) (px)
    {
        int lh = lane >> 5;
        #pragma unroll
        for (int r = 0; r < 16; r++) {
            int pxl = wave * 32 + (r & 3) + 8 * (r >> 2) + 4 * lh;
            E[pxl * 33 + la] = acc[r];
        }
    }
    __syncthreads();
    {
        size_t base = ((size_t)(n * H_ + y) * W_ + xb) * 18;
        #pragma unroll
        for (int k = 0; k < 9; k++) {
            int f = tid + k * 256;
            int pp = f / 18, oc = f % 18;
            off_ws[base + f] = E[pp * 33 + oc] + b_off[oc];
        }
    }
}

// ---------------------------------------------------------------------------
// Bilinear metadata: 4 weights (validity folded) + 4 clamped linear offsets
// ---------------------------------------------------------------------------
__device__ __forceinline__ void bilin_meta(float py, float px,
        float& w00, float& w01, float& w10, float& w11,
        int& o00, int& o01, int& o10, int& o11) {
    float fy0 = floorf(py), fx0 = floorf(px);
    int iy0 = (int)fy0, ix0 = (int)fx0;
    int iy1 = iy0 + 1,  ix1 = ix0 + 1;
    float ly = py - fy0, lx = px - fx0;
    float hy = 1.f - ly, hx = 1.f - lx;
    bool y0ok = (iy0 >= 0) && (iy0 < H_);
    bool y1ok = (iy1 >= 0) && (iy1 < H_);
    bool x0ok = (ix0 >= 0) && (ix0 < W_);
    bool x1ok = (ix1 >= 0) && (ix1 < W_);
    w00 = hy * hx * ((y0ok && x0ok) ? 1.f : 0.f);
    w01 = hy * lx * ((y0ok && x1ok) ? 1.f : 0.f);
    w10 = ly * hx * ((y1ok && x0ok) ? 1.f : 0.f);
    w11 = ly * lx * ((y1ok && x1ok) ? 1.f : 0.f);
    int y0c = min(max(iy0, 0), H_ - 1), y1c = min(max(iy1, 0), H_ - 1);
    int x0c = min(max(ix0, 0), W_ - 1), x1c = min(max(ix1, 0), W_ - 1);
    o00 = y0c * W_ + x0c; o01 = y0c * W_ + x1c;
    o10 = y1c * W_ + x0c; o11 = y1c * W_ + x1c;
}

// ---------------------------------------------------------------------------
// Deformable conv as fused sample+MFMA GEMM: M=128px/block, K=576, N=64.
// Gather from NHWC-bf16: per corner, a lane's 32-ch half = 64 B = one full
// cacheline via 4 dwordx4 (100% line use; 16 loads/thread/tap vs r0's 128).
// Unpack bf16->f32 (1 shl), bilinear in f32, pack back. One-pass epilogue.
// ---------------------------------------------------------------------------
__global__ __launch_bounds__(256, 4) void k_deform(
        const unsigned short* __restrict__ x_tb,
        const float* __restrict__ off_ws,
        const unsigned short* __restrict__ wTb,
        const float* __restrict__ b_def,
        float* __restrict__ out) {
    __shared__ __align__(16) char smem[34304];
    char* S  = smem;              // [128][68] bf16 = 17408 B
    float* E = (float*)smem;      // [128][67] f32 = 34304 B (one-pass epilogue)

    int tid = threadIdx.x;
    int b = blockIdx.x;
    int n = b & 7;                 // image <-> XCD for L2 locality
    int lidx = b >> 3;
    int y = lidx >> 2;
    int xb = (lidx & 3) << 7;
    int lane = tid & 63, wave = tid >> 6;
    int p = tid & 127, cg = tid >> 7;
    int la = lane & 31, kh = lane >> 5;

    f16v acc0, acc1;
    #pragma unroll
    for (int r = 0; r < 16; r++) { acc0[r] = 0.f; acc1[r] = 0.f; }

    const char* xtn = (const char*)x_tb + ((size_t)n * HW_ << 7) + cg * 64;
    size_t pix = (size_t)(n * H_ + y) * W_ + xb + p;
    const f2v* offp = (const f2v*)off_ws + pix * 9;
    char* sp = S + p * 136 + cg * 64;

    for (int t = 0; t < NTAP; t++) {
        // meta + corner addresses BEFORE the barrier (offp latency hides)
        f2v od = offp[t];
        float py = (float)(y + (t / 3) - 1) + od[0];
        float pxf = (float)(xb + p + (t % 3) - 1) + od[1];
        float w00, w01, w10, w11;
        int o00, o01, o10, o11;
        bilin_meta(py, pxf, w00, w01, w10, w11, o00, o01, o10, o11);
        const char* a00 = xtn + ((size_t)o00 << 7);
        const char* a01 = xtn + ((size_t)o01 << 7);
        const char* a10 = xtn + ((size_t)o10 << 7);
        const char* a11 = xtn + ((size_t)o11 << 7);

        __syncthreads();           // S readers from prev tap done
        // 4 groups x 8 channels: 4 short8 loads (one per corner) per group
        #pragma unroll
        for (int g = 0; g < 4; g++) {
            s8v c00 = *(const s8v*)(a00 + g * 16);
            s8v c01 = *(const s8v*)(a01 + g * 16);
            s8v c10 = *(const s8v*)(a10 + g * 16);
            s8v c11 = *(const s8v*)(a11 + g * 16);
            unsigned u[4];
            #pragma unroll
            for (int h = 0; h < 4; h++) {
                float v0 = w00 * bf2f((unsigned short)c00[2 * h]);
                v0 = fmaf(w01, bf2f((unsigned short)c01[2 * h]), v0);
                v0 = fmaf(w10, bf2f((unsigned short)c10[2 * h]), v0);
                v0 = fmaf(w11, bf2f((unsigned short)c11[2 * h]), v0);
                float v1 = w00 * bf2f((unsigned short)c00[2 * h + 1]);
                v1 = fmaf(w01, bf2f((unsigned short)c01[2 * h + 1]), v1);
                v1 = fmaf(w10, bf2f((unsigned short)c10[2 * h + 1]), v1);
                v1 = fmaf(w11, bf2f((unsigned short)c11[2 * h + 1]), v1);
                u[h] = packbf(v0, v1);
            }
            *(unsigned long long*)(sp + g * 16) =
                (unsigned long long)u[0] | ((unsigned long long)u[1] << 32);
            *(unsigned long long*)(sp + g * 16 + 8) =
                (unsigned long long)u[2] | ((unsigned long long)u[3] << 32);
        }
        __syncthreads();
        // MFMA; B fragments straight from global (L1/L2-resident 72 KB table)
        {
            const char* ap = S + (wave * 32 + la) * 136 + kh * 16;
            const char* gb = (const char*)wTb + t * 8192 + la * 128 + kh * 16;
            #pragma unroll
            for (int ks = 0; ks < 4; ks++) {
                s8v a, b0, b1;
                *(long*)&a = *(const long*)ap;
                *((long*)&a + 1) = *(const long*)(ap + 8);
                b0 = *(const s8v*)(gb + ks * 32);
                b1 = *(const s8v*)(gb + 4096 + ks * 32);
                ap += 32;
                acc0 = __builtin_amdgcn_mfma_f32_32x32x16_bf16(a, b0, acc0, 0, 0, 0);
                acc1 = __builtin_amdgcn_mfma_f32_32x32x16_bf16(a, b1, acc1, 0, 0, 0);
            }
        }
    }
    __syncthreads();
    // one-pass epilogue: acc -> E [px][67] -> coalesced store
    {
        int lh = lane >> 5;
        #pragma unroll
        for (int r = 0; r < 16; r++) {
            int pxl = wave * 32 + (r & 3) + 8 * (r >> 2) + 4 * lh;
            E[pxl * 67 + la] = acc0[r];
            E[pxl * 67 + 32 + la] = acc1[r];
        }
    }
    __syncthreads();
    {
        int p0 = tid & 63;
        #pragma unroll
        for (int cb = 0; cb < 16; cb++) {
            int co = (cb << 2) + (tid >> 6);
            float bv = b_def[co];
            size_t ob = ((size_t)(n * CO_ + co) * H_ + y) * W_ + xb;
            out[ob + p0]      = E[p0 * 67 + co] + bv;
            out[ob + p0 + 64] = E[(p0 + 64) * 67 + co] + bv;
        }
    }
}

// ---------------------------------------------------------------------------
extern "C" void kernel_launch(void* const* d_in, const int* in_sizes, int n_in,
                              void* d_out, int out_size, void* d_ws, size_t ws_size,
                              hipStream_t stream) {
    const float* x     = (const float*)d_in[0];
    const float* w_off = (const float*)d_in[1];
    const float* b_off = (const float*)d_in[2];
    const float* w_def = (const float*)d_in[3];
    const float* b_def = (const float*)d_in[4];
    float* out = (float*)d_out;

    // ws: wTb @0 (72K), wOb @80K (36K), off_ws @256K (37.75 MB),
    //     x_tb NHWC bf16 @40M (67.1 MB) -> total ~108 MB
    unsigned short* wTb  = (unsigned short*)d_ws;
    unsigned short* wOb  = (unsigned short*)((char*)d_ws + 80 * 1024);
    float* off_ws        = (float*)((char*)d_ws + 256 * 1024);
    unsigned short* x_tb = (unsigned short*)((char*)d_ws + (size_t)40 * 1024 * 1024);

    hipLaunchKernelGGL(k_prep_w, dim3(144), dim3(256), 0, stream,
                       w_def, w_off, wTb, wOb);
    hipLaunchKernelGGL(k_tr, dim3(8192), dim3(256), 0, stream, x, x_tb);
    hipLaunchKernelGGL(k_off_mfma, dim3(4096), dim3(256), 0, stream,
                       x_tb, wOb, b_off, off_ws);
    hipLaunchKernelGGL(k_deform, dim3(4096), dim3(256), 0, stream,
                       x_tb, off_ws, wTb, b_def, out);
}